// Round 6
// baseline (202.305 us; speedup 1.0000x reference)
//
#include <hip/hip_runtime.h>

// WordSAGE on MI355X — fp32 in/out. Round-16 = round-15 with the compile fix:
// __builtin_nontemporal_load needs ext_vector_type, not HIP_vector_type.
//   k_prep : [edge fillpad x4/thread, 625 blocks + nontemporal edge loads &
//            csr stores (cut L2 pollution / RFO churn) | gene->GH | pack].
//   k_mega : r14 body + __launch_bounds__(512,4): LDS caps blocks at 3/CU
//            but default bounds made compiler allocate only 52 VGPR ->
//            B-load/gather prefetch depth ~2 -> serial L2-latency rounds.
//            128-reg budget lets the unrolled layer1 B loads and the 8-wide
//            gather batch actually stay in flight (r3/r4 proved occupancy
//            does not matter for this kernel).
// Precision: weights/agg/h split hi+lo bf16; train & gene hi-only (RNE).

#define NG 2500
#define NT 20000
#define NE 640000
#define NCLS 16
#define CAP 96

typedef unsigned short u16;
typedef unsigned int u32;

typedef float f32x4 __attribute__((ext_vector_type(4)));
typedef int i32x4 __attribute__((ext_vector_type(4)));
typedef __bf16 bf16x8 __attribute__((ext_vector_type(8)));

__device__ __forceinline__ float b2f(u16 u) { return __uint_as_float(((u32)u) << 16); }
__device__ __forceinline__ float blo(u32 p) { return __uint_as_float(p << 16); }
__device__ __forceinline__ float bhi(u32 p) { return __uint_as_float(p & 0xffff0000u); }
__device__ __forceinline__ u16 f2b(float f) {  // RNE fp32->bf16
    u32 u = __float_as_uint(f);
    return (u16)((u + 0x7fffu + ((u >> 16) & 1u)) >> 16);
}

// ---- sizes ---------------------------------------------------------------
#define B1N 81920   // K=640: train k 0..499, zero 500..511, agg 512..639; N=128
#define B2N 32768   // K=256: h1 (W2s) 0..127, agg (W2n) 128..255; N=128
#define B3N 16384   // K=128 Wc1, N=128
#define B4N 2048    // K=128 Wc2, N=16
#define NEB 625     // edge blocks (4 edges/thread)
#define GNB 625     // gene-convert blocks
#define PKB 520     // pack blocks

// ---- fused prep -----------------------------------------------------------
__global__ __launch_bounds__(256) void k_prep(
    const int* __restrict__ esrc, const int* __restrict__ edst,
    int* __restrict__ cnt, u16* __restrict__ csr,
    const float* __restrict__ gene, u32* __restrict__ GH32,
    const float* __restrict__ W1n, const float* __restrict__ W1s,
    const float* __restrict__ W2n, const float* __restrict__ W2s,
    const float* __restrict__ Wc1, const float* __restrict__ Wc2,
    u16* __restrict__ B1h, u16* __restrict__ B1l,
    u16* __restrict__ B2h, u16* __restrict__ B2l,
    u16* __restrict__ B3h, u16* __restrict__ B3l,
    u16* __restrict__ B4h, u16* __restrict__ B4l) {
    int blk = blockIdx.x, t = threadIdx.x;
    if (blk < NEB) {
        int e0 = (blk * 256 + t) * 4;
        i32x4 s4 = __builtin_nontemporal_load((const i32x4*)(esrc + e0));
        i32x4 d4 = __builtin_nontemporal_load((const i32x4*)(edst + e0));
        int ss[4] = {s4.x, s4.y, s4.z, s4.w};
        int dd[4] = {d4.x, d4.y, d4.z, d4.w};
#pragma unroll
        for (int i = 0; i < 4; ++i) {   // 4 independent atomic chains
            unsigned d = (unsigned)dd[i];
            if (d < NT) {
                int slot = atomicAdd(&cnt[d], 1);
                if (slot < CAP)
                    __builtin_nontemporal_store((u16)ss[i],
                                                csr + (size_t)d * CAP + slot);
            }
        }
        return;
    }
    if (blk < NEB + GNB) {
        int idx = (blk - NEB) * 256 + t;  // < 160000
        float2 v = ((const float2*)gene)[idx];
        GH32[idx] = (u32)f2b(v.x) | ((u32)f2b(v.y) << 16);
        return;
    }
    // ---- weight pack (split hi/lo, B-fragment order) ----
    int idx = (blk - NEB - GNB) * 256 + t;
    float v = 0.f;
    u16 *ph = 0, *pl = 0;
    int off = 0;
    if (idx < B1N) {
        int j = idx & 7, l = (idx >> 3) & 63, rest = idx >> 9;
        int g = rest & 7, kk = rest >> 3;
        int k = kk * 32 + ((l >> 4) << 3) + j, n = (g << 4) + (l & 15);
        if (k < 500) v = W1s[k * 128 + n];
        else if (k >= 512) v = W1n[(k - 512) * 128 + n];
        ph = B1h; pl = B1l; off = idx;
    } else if (idx < B1N + B2N) {
        int e = idx - B1N;
        int j = e & 7, l = (e >> 3) & 63, rest = e >> 9;
        int g = rest & 7, kk = rest >> 3;
        int k = kk * 32 + ((l >> 4) << 3) + j, n = (g << 4) + (l & 15);
        v = (k < 128) ? W2s[k * 128 + n] : W2n[(k - 128) * 128 + n];
        ph = B2h; pl = B2l; off = e;
    } else if (idx < B1N + B2N + B3N) {
        int e = idx - (B1N + B2N);
        int j = e & 7, l = (e >> 3) & 63, rest = e >> 9;
        int g = rest & 7, kk = rest >> 3;
        int k = kk * 32 + ((l >> 4) << 3) + j, n = (g << 4) + (l & 15);
        v = Wc1[k * 128 + n];
        ph = B3h; pl = B3l; off = e;
    } else if (idx < B1N + B2N + B3N + B4N) {
        int e = idx - (B1N + B2N + B3N);
        int j = e & 7, l = (e >> 3) & 63, kk = e >> 9;
        int k = kk * 32 + ((l >> 4) << 3) + j, n = l & 15;
        v = Wc2[k * 16 + n];
        ph = B4h; pl = B4l; off = e;
    }
    if (ph) {
        u16 hi = f2b(v);
        u16 lo = f2b(v - b2f(hi));
        ph[off] = hi;
        pl[off] = lo;
    }
}

// ---- fused gather + stage + 4-layer MFMA ----------------------------------
// Block: 512 thr (8 waves), 32 rows (2 tiles). wave = col-group g (0..7);
// each wave handles BOTH row-tiles (acc0/acc1) -> B bytes read once/block.
// Shared pool (u16 units):
//   SAGh @0      [32*136]    SAGl @4352  [32*136]
//   S1h  @8704   [32*136]    S1l  @13056 [32*136]
//   S2h  @17408  [32*136]    S2l  @21760 [32*136]
//   TS   @8704   [32*520]  (train tile bf16, overlays S1h..S2l; dead after
//                           layer1 kk0..15 -> barrier before S1 epilogue)
__global__ __launch_bounds__(512, 4) void k_mega(
    const int* __restrict__ cnt, const u16* __restrict__ csr,
    const u16* __restrict__ GH, const float* __restrict__ train,
    const u16* __restrict__ B1h, const u16* __restrict__ B1l,
    const u16* __restrict__ B2h, const u16* __restrict__ B2l,
    const u16* __restrict__ B3h, const u16* __restrict__ B3l,
    const u16* __restrict__ B4h, const u16* __restrict__ B4l,
    const float* __restrict__ b1, const float* __restrict__ b2,
    const float* __restrict__ bc1, const float* __restrict__ bc2,
    float* __restrict__ out) {
    __shared__ __align__(16) u16 SMEM[26112];   // 52224 B
    u16* SAGh = SMEM;
    u16* SAGl = SMEM + 4352;
    u16* S1h = SMEM + 8704;
    u16* S1l = SMEM + 13056;
    u16* S2h = SMEM + 17408;
    u16* S2l = SMEM + 21760;
    u16* TS = SMEM + 8704;                      // overlays S1h..S2l

    int t = threadIdx.x;
    int row0 = blockIdx.x * 32;

    // ---- phase 0a: issue train-tile loads (latency hides under gather) ----
    float4 st[8];
    {
        const float4* tb = (const float4*)(train + (size_t)row0 * 500);
#pragma unroll
        for (int i = 0; i < 7; ++i) st[i] = tb[t + i * 512];
        if (t < 416) st[7] = tb[t + 3584];      // 4000 float4 = 32 rows x 125
    }

    // ---- phase 0b: gather-mean of gene-hi into SAG (batched indices) ----
    {
        int r = t >> 4, cg = t & 15;           // row 0..31, col-group 0..15
        int d = row0 + r;
        int ctrue = cnt[d];
        int c = ctrue > CAP ? CAP : ctrue;
        const u16* crow = csr + (size_t)d * CAP;
        float a[8];
#pragma unroll
        for (int p = 0; p < 8; ++p) a[p] = 0.f;

#define GHL(s) (*(const uint4*)(GH + (size_t)(s) * 128 + cg * 8))
#define ACC(p)                                   \
        do {                                     \
            a[0] += blo((p).x); a[1] += bhi((p).x); \
            a[2] += blo((p).y); a[3] += bhi((p).y); \
            a[4] += blo((p).z); a[5] += bhi((p).z); \
            a[6] += blo((p).w); a[7] += bhi((p).w); \
        } while (0)

        int j = 0;
        for (; j + 8 <= c; j += 8) {           // 1 idx load -> 8 row loads
            uint4 i4 = *(const uint4*)(crow + j);
            int s0 = i4.x & 0xffff, s1 = i4.x >> 16;
            int s2 = i4.y & 0xffff, s3 = i4.y >> 16;
            int s4 = i4.z & 0xffff, s5 = i4.z >> 16;
            int s6 = i4.w & 0xffff, s7 = i4.w >> 16;
            uint4 p0 = GHL(s0); uint4 p1 = GHL(s1);
            uint4 p2 = GHL(s2); uint4 p3 = GHL(s3);
            uint4 p4 = GHL(s4); uint4 p5 = GHL(s5);
            uint4 p6 = GHL(s6); uint4 p7 = GHL(s7);
            ACC(p0); ACC(p1); ACC(p2); ACC(p3);
            ACC(p4); ACC(p5); ACC(p6); ACC(p7);
        }
        if (j < c) {                            // clamped predicated tail batch
            uint4 i4 = *(const uint4*)(crow + j);  // j<=88 -> slots j..j+7 <96
            u32 w[4] = {i4.x, i4.y, i4.z, i4.w};
#pragma unroll
            for (int k = 0; k < 8; ++k) {
                int s = (int)((w[k >> 1] >> ((k & 1) * 16)) & 0xffffu);
                bool live = (j + k) < c;
                s = live ? s : 0;               // garbage slots never derefed
                uint4 p = GHL(s);
                if (live) ACC(p);
            }
        }
#undef GHL
#undef ACC

        float inv = (ctrue > 0) ? 1.f / (float)ctrue : 0.f;
        int base = (r * 136 + cg * 8) >> 1;    // u32 index (even)
        u32* SH = (u32*)SAGh;
        u32* SL = (u32*)SAGl;
#pragma unroll
        for (int p = 0; p < 4; ++p) {
            float x = a[2 * p] * inv, y = a[2 * p + 1] * inv;
            u16 hx = f2b(x), hy = f2b(y);
            SH[base + p] = (u32)hx | ((u32)hy << 16);
            SL[base + p] = (u32)f2b(x - b2f(hx)) | ((u32)f2b(y - b2f(hy)) << 16);
        }
    }

    // ---- phase 0c: convert staged tile -> TS (row-major [32][520] bf16) ----
    {
        u32* T32 = (u32*)TS;
#pragma unroll
        for (int i = 0; i < 8; ++i) {
            int idx = t + i * 512;
            if (i == 7 && t >= 416) break;
            int r = idx / 125, c4 = idx - r * 125;
            int base = r * 260 + c4 * 2;       // u32 units; row stride 520 u16
            T32[base] = (u32)f2b(st[i].x) | ((u32)f2b(st[i].y) << 16);
            T32[base + 1] = (u32)f2b(st[i].z) | ((u32)f2b(st[i].w) << 16);
        }
        if (t < 192) {                          // zero cols 500..511
            int r = t / 6, c = t - r * 6;
            T32[r * 260 + 250 + c] = 0;
        }
    }
    __syncthreads();

    int lane = t & 63, g = t >> 6;  // wave index = col-group 0..7
    int m = lane & 15, q = lane >> 4, n16 = lane & 15;

    int hr0 = m * 136 + q * 8;
    int hr1 = (16 + m) * 136 + q * 8;
    int cr0 = q * 4, cr1 = 16 + q * 4;
    const f32x4 z4 = {0.f, 0.f, 0.f, 0.f};
    f32x4 acc0 = z4, acc1 = z4;

    // ---- layer1: K=640 (train bf16 kk0..15 from TS; agg kk16..19 SAG) ----
    const u16* tA0 = TS + m * 520 + q * 8;
    const u16* tA1 = TS + (16 + m) * 520 + q * 8;
#pragma unroll
    for (int kk = 0; kk < 16; ++kk) {
        bf16x8 a0 = *(const bf16x8*)(tA0 + kk * 32);
        bf16x8 a1 = *(const bf16x8*)(tA1 + kk * 32);
        size_t bo = ((size_t)(kk * 8 + g) * 64 + lane) * 8;
        bf16x8 bh = *(const bf16x8*)(B1h + bo);
        bf16x8 bl = *(const bf16x8*)(B1l + bo);
        acc0 = __builtin_amdgcn_mfma_f32_16x16x32_bf16(a0, bh, acc0, 0, 0, 0);
        acc0 = __builtin_amdgcn_mfma_f32_16x16x32_bf16(a0, bl, acc0, 0, 0, 0);
        acc1 = __builtin_amdgcn_mfma_f32_16x16x32_bf16(a1, bh, acc1, 0, 0, 0);
        acc1 = __builtin_amdgcn_mfma_f32_16x16x32_bf16(a1, bl, acc1, 0, 0, 0);
    }
#pragma unroll
    for (int kk = 16; kk < 20; ++kk) {
        int o = (kk - 16) * 32;
        bf16x8 ah0 = *(const bf16x8*)(SAGh + hr0 + o);
        bf16x8 al0 = *(const bf16x8*)(SAGl + hr0 + o);
        bf16x8 ah1 = *(const bf16x8*)(SAGh + hr1 + o);
        bf16x8 al1 = *(const bf16x8*)(SAGl + hr1 + o);
        size_t bo = ((size_t)(kk * 8 + g) * 64 + lane) * 8;
        bf16x8 bh = *(const bf16x8*)(B1h + bo);
        bf16x8 bl = *(const bf16x8*)(B1l + bo);
        acc0 = __builtin_amdgcn_mfma_f32_16x16x32_bf16(ah0, bh, acc0, 0, 0, 0);
        acc0 = __builtin_amdgcn_mfma_f32_16x16x32_bf16(ah0, bl, acc0, 0, 0, 0);
        acc0 = __builtin_amdgcn_mfma_f32_16x16x32_bf16(al0, bh, acc0, 0, 0, 0);
        acc1 = __builtin_amdgcn_mfma_f32_16x16x32_bf16(ah1, bh, acc1, 0, 0, 0);
        acc1 = __builtin_amdgcn_mfma_f32_16x16x32_bf16(ah1, bl, acc1, 0, 0, 0);
        acc1 = __builtin_amdgcn_mfma_f32_16x16x32_bf16(al1, bh, acc1, 0, 0, 0);
    }
    __syncthreads();   // TS (overlaid on S1/S2) dead only when ALL waves passed
    {
        int n = g * 16 + n16;
        float bias = b1[n];
#pragma unroll
        for (int rg = 0; rg < 4; ++rg) {
            float v0 = acc0[rg] + bias; v0 = v0 > 0.f ? v0 : 0.f;
            float v1 = acc1[rg] + bias; v1 = v1 > 0.f ? v1 : 0.f;
            u16 h0 = f2b(v0), h1v = f2b(v1);
            S1h[(cr0 + rg) * 136 + n] = h0; S1l[(cr0 + rg) * 136 + n] = f2b(v0 - b2f(h0));
            S1h[(cr1 + rg) * 136 + n] = h1v; S1l[(cr1 + rg) * 136 + n] = f2b(v1 - b2f(h1v));
        }
    }
    __syncthreads();

    // ---- layer2: K=256 (h1 kk0..3 S1; agg kk4..7 SAG) ----
    acc0 = z4; acc1 = z4;
#pragma unroll
    for (int kk = 0; kk < 8; ++kk) {
        const u16* Ph = (kk < 4) ? S1h : SAGh;
        const u16* Pl = (kk < 4) ? S1l : SAGl;
        int o = (kk & 3) * 32;
        bf16x8 ah0 = *(const bf16x8*)(Ph + hr0 + o);
        bf16x8 al0 = *(const bf16x8*)(Pl + hr0 + o);
        bf16x8 ah1 = *(const bf16x8*)(Ph + hr1 + o);
        bf16x8 al1 = *(const bf16x8*)(Pl + hr1 + o);
        size_t bo = ((size_t)(kk * 8 + g) * 64 + lane) * 8;
        bf16x8 bh = *(const bf16x8*)(B2h + bo);
        bf16x8 bl = *(const bf16x8*)(B2l + bo);
        acc0 = __builtin_amdgcn_mfma_f32_16x16x32_bf16(ah0, bh, acc0, 0, 0, 0);
        acc0 = __builtin_amdgcn_mfma_f32_16x16x32_bf16(ah0, bl, acc0, 0, 0, 0);
        acc0 = __builtin_amdgcn_mfma_f32_16x16x32_bf16(al0, bh, acc0, 0, 0, 0);
        acc1 = __builtin_amdgcn_mfma_f32_16x16x32_bf16(ah1, bh, acc1, 0, 0, 0);
        acc1 = __builtin_amdgcn_mfma_f32_16x16x32_bf16(ah1, bl, acc1, 0, 0, 0);
        acc1 = __builtin_amdgcn_mfma_f32_16x16x32_bf16(al1, bh, acc1, 0, 0, 0);
    }
    {
        int n = g * 16 + n16;
        float bias = b2[n];
#pragma unroll
        for (int rg = 0; rg < 4; ++rg) {
            float v0 = acc0[rg] + bias; v0 = v0 > 0.f ? v0 : 0.f;
            float v1 = acc1[rg] + bias; v1 = v1 > 0.f ? v1 : 0.f;
            u16 h0 = f2b(v0), h1v = f2b(v1);
            S2h[(cr0 + rg) * 136 + n] = h0; S2l[(cr0 + rg) * 136 + n] = f2b(v0 - b2f(h0));
            S2h[(cr1 + rg) * 136 + n] = h1v; S2l[(cr1 + rg) * 136 + n] = f2b(v1 - b2f(h1v));
        }
    }
    __syncthreads();

    // ---- layer3: K=128 (h2 S2) -> S1 ----
    acc0 = z4; acc1 = z4;
#pragma unroll
    for (int kk = 0; kk < 4; ++kk) {
        int o = kk * 32;
        bf16x8 ah0 = *(const bf16x8*)(S2h + hr0 + o);
        bf16x8 al0 = *(const bf16x8*)(S2l + hr0 + o);
        bf16x8 ah1 = *(const bf16x8*)(S2h + hr1 + o);
        bf16x8 al1 = *(const bf16x8*)(S2l + hr1 + o);
        size_t bo = ((size_t)(kk * 8 + g) * 64 + lane) * 8;
        bf16x8 bh = *(const bf16x8*)(B3h + bo);
        bf16x8 bl = *(const bf16x8*)(B3l + bo);
        acc0 = __builtin_amdgcn_mfma_f32_16x16x32_bf16(ah0, bh, acc0, 0, 0, 0);
        acc0 = __builtin_amdgcn_mfma_f32_16x16x32_bf16(ah0, bl, acc0, 0, 0, 0);
        acc0 = __builtin_amdgcn_mfma_f32_16x16x32_bf16(al0, bh, acc0, 0, 0, 0);
        acc1 = __builtin_amdgcn_mfma_f32_16x16x32_bf16(ah1, bh, acc1, 0, 0, 0);
        acc1 = __builtin_amdgcn_mfma_f32_16x16x32_bf16(ah1, bl, acc1, 0, 0, 0);
        acc1 = __builtin_amdgcn_mfma_f32_16x16x32_bf16(al1, bh, acc1, 0, 0, 0);
    }
    {
        int n = g * 16 + n16;
        float bias = bc1[n];
#pragma unroll
        for (int rg = 0; rg < 4; ++rg) {
            float v0 = acc0[rg] + bias; v0 = v0 > 0.f ? v0 : 0.f;
            float v1 = acc1[rg] + bias; v1 = v1 > 0.f ? v1 : 0.f;
            u16 h0 = f2b(v0), h1v = f2b(v1);
            S1h[(cr0 + rg) * 136 + n] = h0; S1l[(cr0 + rg) * 136 + n] = f2b(v0 - b2f(h0));
            S1h[(cr1 + rg) * 136 + n] = h1v; S1l[(cr1 + rg) * 136 + n] = f2b(v1 - b2f(h1v));
        }
    }
    __syncthreads();

    // ---- layer4: K=128, N=16 (waves 0,1 = tiles 0,1) ----
    if (g < 2) {
        int hr = (g == 0) ? hr0 : hr1;
        int cr = (g == 0) ? cr0 : cr1;
        f32x4 a4 = z4;
#pragma unroll
        for (int kk = 0; kk < 4; ++kk) {
            bf16x8 ah = *(const bf16x8*)(S1h + hr + kk * 32);
            bf16x8 al = *(const bf16x8*)(S1l + hr + kk * 32);
            size_t bo = ((size_t)kk * 64 + lane) * 8;
            bf16x8 bh = *(const bf16x8*)(B4h + bo);
            bf16x8 bl = *(const bf16x8*)(B4l + bo);
            a4 = __builtin_amdgcn_mfma_f32_16x16x32_bf16(ah, bh, a4, 0, 0, 0);
            a4 = __builtin_amdgcn_mfma_f32_16x16x32_bf16(ah, bl, a4, 0, 0, 0);
            a4 = __builtin_amdgcn_mfma_f32_16x16x32_bf16(al, bh, a4, 0, 0, 0);
        }
        float bias = bc2[n16];
#pragma unroll
        for (int rg = 0; rg < 4; ++rg)
            out[(size_t)(row0 + cr + rg) * NCLS + n16] = a4[rg] + bias;
    }
}

extern "C" void kernel_launch(void* const* d_in, const int* in_sizes, int n_in,
                              void* d_out, int out_size, void* d_ws, size_t ws_size,
                              hipStream_t stream) {
    const float* gene = (const float*)d_in[0];
    const float* train = (const float*)d_in[1];
    const int* esrc = (const int*)d_in[2];
    const int* edst = (const int*)d_in[3];

    char* ws = (char*)d_ws;
    int* cnt = (int*)(ws + 0);              //    80000
    u16* csr = (u16*)(ws + 80000);          //  3840000
    u16* GH = (u16*)(ws + 3920000);         //   640000 (2500*128 u16)
    u16* B1h = (u16*)(ws + 4560000);        //   163840
    u16* B1l = (u16*)(ws + 4723840);        //   163840
    u16* B2h = (u16*)(ws + 4887680);        //    65536
    u16* B2l = (u16*)(ws + 4953216);        //    65536
    u16* B3h = (u16*)(ws + 5018752);        //    32768
    u16* B3l = (u16*)(ws + 5051520);        //    32768
    u16* B4h = (u16*)(ws + 5084288);        //     4096
    u16* B4l = (u16*)(ws + 5088384);        //     4096
    // total 5,092,480 B

    hipMemsetAsync(cnt, 0, NT * sizeof(int), stream);
    k_prep<<<NEB + GNB + PKB, 256, 0, stream>>>(
        esrc, edst, cnt, csr, gene, (u32*)GH,
        (const float*)d_in[4], (const float*)d_in[5], (const float*)d_in[7],
        (const float*)d_in[8], (const float*)d_in[10], (const float*)d_in[12],
        B1h, B1l, B2h, B2l, B3h, B3l, B4h, B4l);
    k_mega<<<NT / 32, 512, 0, stream>>>(
        cnt, csr, GH, train, B1h, B1l, B2h, B2l, B3h, B3l, B4h, B4l,
        (const float*)d_in[6], (const float*)d_in[9], (const float*)d_in[11],
        (const float*)d_in[13], (float*)d_out);
}

// Round 7
// 172.475 us; speedup vs baseline: 1.1730x; 1.1730x over previous
//
#include <hip/hip_runtime.h>

// WordSAGE on MI355X — fp32 in/out. Round-17 (2 kernels + memset):
//   k_prep : reverted to round-2 form — edge fillpad x4/thread, 625 blocks,
//            PLAIN loads/stores (r6's nontemporal csr stores bypassed L2
//            write-combining: WRITE_SIZE 34->42.6MB, +20us. Never again.)
//   k_mega : SOFTWARE-PIPELINED phase fusion. Gather batches (8 GH rows via
//            one uint4 index load) interleave with layer1's TS-kk MFMA quads:
//            issue batch b -> 16 MFMA + 8 ds_read (~400cyc, covers L2 RT) ->
//            acc batch b -> issue b+1. 4 rounds cover avg c=32; residual loop
//            for c>32; predicated tail. Accumulation order per thread is
//            unchanged -> bit-identical. __launch_bounds__(512,3) for the
//            ~110 VGPR the in-flight batch needs (2 blocks/CU residency;
//            r3/r4 proved wave count isn't the lever, ILP is).
// Precision: weights/agg/h split hi+lo bf16; train & gene hi-only (RNE).

#define NG 2500
#define NT 20000
#define NE 640000
#define NCLS 16
#define CAP 96

typedef unsigned short u16;
typedef unsigned int u32;

typedef float f32x4 __attribute__((ext_vector_type(4)));
typedef __bf16 bf16x8 __attribute__((ext_vector_type(8)));

__device__ __forceinline__ float b2f(u16 u) { return __uint_as_float(((u32)u) << 16); }
__device__ __forceinline__ float blo(u32 p) { return __uint_as_float(p << 16); }
__device__ __forceinline__ float bhi(u32 p) { return __uint_as_float(p & 0xffff0000u); }
__device__ __forceinline__ u16 f2b(float f) {  // RNE fp32->bf16
    u32 u = __float_as_uint(f);
    return (u16)((u + 0x7fffu + ((u >> 16) & 1u)) >> 16);
}

// ---- sizes ---------------------------------------------------------------
#define B1N 81920   // K=640: train k 0..499, zero 500..511, agg 512..639; N=128
#define B2N 32768   // K=256: h1 (W2s) 0..127, agg (W2n) 128..255; N=128
#define B3N 16384   // K=128 Wc1, N=128
#define B4N 2048    // K=128 Wc2, N=16
#define NEB 625     // edge blocks (4 edges/thread via int4)
#define GNB 625     // gene-convert blocks
#define PKB 520     // pack blocks

// ---- fused prep -----------------------------------------------------------
__global__ __launch_bounds__(256) void k_prep(
    const int* __restrict__ esrc, const int* __restrict__ edst,
    int* __restrict__ cnt, u16* __restrict__ csr,
    const float* __restrict__ gene, u32* __restrict__ GH32,
    const float* __restrict__ W1n, const float* __restrict__ W1s,
    const float* __restrict__ W2n, const float* __restrict__ W2s,
    const float* __restrict__ Wc1, const float* __restrict__ Wc2,
    u16* __restrict__ B1h, u16* __restrict__ B1l,
    u16* __restrict__ B2h, u16* __restrict__ B2l,
    u16* __restrict__ B3h, u16* __restrict__ B3l,
    u16* __restrict__ B4h, u16* __restrict__ B4l) {
    int blk = blockIdx.x, t = threadIdx.x;
    if (blk < NEB) {
        int e0 = (blk * 256 + t) * 4;
        const int4 s4 = *(const int4*)(esrc + e0);
        const int4 d4 = *(const int4*)(edst + e0);
        int ss[4] = {s4.x, s4.y, s4.z, s4.w};
        int dd[4] = {d4.x, d4.y, d4.z, d4.w};
#pragma unroll
        for (int i = 0; i < 4; ++i) {   // 4 independent atomic chains
            unsigned d = (unsigned)dd[i];
            if (d < NT) {
                int slot = atomicAdd(&cnt[d], 1);
                if (slot < CAP) csr[(size_t)d * CAP + slot] = (u16)ss[i];
            }
        }
        return;
    }
    if (blk < NEB + GNB) {
        int idx = (blk - NEB) * 256 + t;  // < 160000
        float2 v = ((const float2*)gene)[idx];
        GH32[idx] = (u32)f2b(v.x) | ((u32)f2b(v.y) << 16);
        return;
    }
    // ---- weight pack (split hi/lo, B-fragment order) ----
    int idx = (blk - NEB - GNB) * 256 + t;
    float v = 0.f;
    u16 *ph = 0, *pl = 0;
    int off = 0;
    if (idx < B1N) {
        int j = idx & 7, l = (idx >> 3) & 63, rest = idx >> 9;
        int g = rest & 7, kk = rest >> 3;
        int k = kk * 32 + ((l >> 4) << 3) + j, n = (g << 4) + (l & 15);
        if (k < 500) v = W1s[k * 128 + n];
        else if (k >= 512) v = W1n[(k - 512) * 128 + n];
        ph = B1h; pl = B1l; off = idx;
    } else if (idx < B1N + B2N) {
        int e = idx - B1N;
        int j = e & 7, l = (e >> 3) & 63, rest = e >> 9;
        int g = rest & 7, kk = rest >> 3;
        int k = kk * 32 + ((l >> 4) << 3) + j, n = (g << 4) + (l & 15);
        v = (k < 128) ? W2s[k * 128 + n] : W2n[(k - 128) * 128 + n];
        ph = B2h; pl = B2l; off = e;
    } else if (idx < B1N + B2N + B3N) {
        int e = idx - (B1N + B2N);
        int j = e & 7, l = (e >> 3) & 63, rest = e >> 9;
        int g = rest & 7, kk = rest >> 3;
        int k = kk * 32 + ((l >> 4) << 3) + j, n = (g << 4) + (l & 15);
        v = Wc1[k * 128 + n];
        ph = B3h; pl = B3l; off = e;
    } else if (idx < B1N + B2N + B3N + B4N) {
        int e = idx - (B1N + B2N + B3N);
        int j = e & 7, l = (e >> 3) & 63, kk = e >> 9;
        int k = kk * 32 + ((l >> 4) << 3) + j, n = l & 15;
        v = Wc2[k * 16 + n];
        ph = B4h; pl = B4l; off = e;
    }
    if (ph) {
        u16 hi = f2b(v);
        u16 lo = f2b(v - b2f(hi));
        ph[off] = hi;
        pl[off] = lo;
    }
}

// ---- fused gather + stage + 4-layer MFMA ----------------------------------
// Block: 512 thr (8 waves), 32 rows (2 tiles). wave = col-group g (0..7);
// each wave handles BOTH row-tiles (acc0/acc1) -> B bytes read once/block.
// Shared pool (u16 units):
//   SAGh @0      [32*136]    SAGl @4352  [32*136]
//   S1h  @8704   [32*136]    S1l  @13056 [32*136]
//   S2h  @17408  [32*136]    S2l  @21760 [32*136]
//   TS   @8704   [32*520]  (train tile bf16, overlays S1h..S2l; all TS reads
//                           complete before the post-gather barrier)
__global__ __launch_bounds__(512, 3) void k_mega(
    const int* __restrict__ cnt, const u16* __restrict__ csr,
    const u16* __restrict__ GH, const float* __restrict__ train,
    const u16* __restrict__ B1h, const u16* __restrict__ B1l,
    const u16* __restrict__ B2h, const u16* __restrict__ B2l,
    const u16* __restrict__ B3h, const u16* __restrict__ B3l,
    const u16* __restrict__ B4h, const u16* __restrict__ B4l,
    const float* __restrict__ b1, const float* __restrict__ b2,
    const float* __restrict__ bc1, const float* __restrict__ bc2,
    float* __restrict__ out) {
    __shared__ __align__(16) u16 SMEM[26112];   // 52224 B
    u16* SAGh = SMEM;
    u16* SAGl = SMEM + 4352;
    u16* S1h = SMEM + 8704;
    u16* S1l = SMEM + 13056;
    u16* S2h = SMEM + 17408;
    u16* S2l = SMEM + 21760;
    u16* TS = SMEM + 8704;                      // overlays S1h..S2l

    int t = threadIdx.x;
    int row0 = blockIdx.x * 32;

    // ---- phase 0a: issue train-tile loads (latency hides under setup) ----
    float4 st[8];
    {
        const float4* tb = (const float4*)(train + (size_t)row0 * 500);
#pragma unroll
        for (int i = 0; i < 7; ++i) st[i] = tb[t + i * 512];
        if (t < 416) st[7] = tb[t + 3584];      // 4000 float4 = 32 rows x 125
    }

    // ---- gather setup (loads in flight under the TS convert) ----
    int gr = t >> 4, cg = t & 15;              // row 0..31, col-group 0..15
    int d = row0 + gr;
    int ctrue = cnt[d];
    int c = ctrue > CAP ? CAP : ctrue;
    const u16* crow = csr + (size_t)d * CAP;
    int nfull = c >> 3;                        // full batches of 8
    // index quads always in-bounds (csr row has CAP=96 slots)
    uint4 i40 = *(const uint4*)(crow);
    uint4 i41 = *(const uint4*)(crow + 8);
    uint4 i42 = *(const uint4*)(crow + 16);
    uint4 i43 = *(const uint4*)(crow + 24);
    float a[8];
#pragma unroll
    for (int p = 0; p < 8; ++p) a[p] = 0.f;

    // ---- phase 0c: convert staged tile -> TS (row-major [32][520] bf16) ----
    {
        u32* T32 = (u32*)TS;
#pragma unroll
        for (int i = 0; i < 8; ++i) {
            int idx = t + i * 512;
            if (i == 7 && t >= 416) break;
            int r = idx / 125, c4 = idx - r * 125;
            int base = r * 260 + c4 * 2;       // u32 units; row stride 520 u16
            T32[base] = (u32)f2b(st[i].x) | ((u32)f2b(st[i].y) << 16);
            T32[base + 1] = (u32)f2b(st[i].z) | ((u32)f2b(st[i].w) << 16);
        }
        if (t < 192) {                          // zero cols 500..511
            int r = t / 6, c4 = t - r * 6;
            T32[r * 260 + 250 + c4] = 0;
        }
    }
    __syncthreads();

    int lane = t & 63, g = t >> 6;  // wave index = col-group 0..7
    int m = lane & 15, q = lane >> 4, n16 = lane & 15;

    int hr0 = m * 136 + q * 8;
    int hr1 = (16 + m) * 136 + q * 8;
    int cr0 = q * 4, cr1 = 16 + q * 4;
    const f32x4 z4 = {0.f, 0.f, 0.f, 0.f};
    f32x4 acc0 = z4, acc1 = z4;
    const u16* tA0 = TS + m * 520 + q * 8;
    const u16* tA1 = TS + (16 + m) * 520 + q * 8;

#define ACC(p)                                      \
    do {                                            \
        a[0] += blo((p).x); a[1] += bhi((p).x);     \
        a[2] += blo((p).y); a[3] += bhi((p).y);     \
        a[4] += blo((p).z); a[5] += bhi((p).z);     \
        a[6] += blo((p).w); a[7] += bhi((p).w);     \
    } while (0)

    auto GHLoad = [&](int s) -> uint4 {
        return *(const uint4*)(GH + (size_t)s * 128 + cg * 8);
    };
    uint4 P0, P1, P2, P3, P4, P5, P6, P7;
    auto issue8 = [&](uint4 iq) {
        P0 = GHLoad((int)(iq.x & 0xffffu)); P1 = GHLoad((int)(iq.x >> 16));
        P2 = GHLoad((int)(iq.y & 0xffffu)); P3 = GHLoad((int)(iq.y >> 16));
        P4 = GHLoad((int)(iq.z & 0xffffu)); P5 = GHLoad((int)(iq.z >> 16));
        P6 = GHLoad((int)(iq.w & 0xffffu)); P7 = GHLoad((int)(iq.w >> 16));
    };
    auto acc8 = [&]() {
        ACC(P0); ACC(P1); ACC(P2); ACC(P3);
        ACC(P4); ACC(P5); ACC(P6); ACC(P7);
    };
    auto kk4 = [&](int base) {
#pragma unroll
        for (int kk = base; kk < base + 4; ++kk) {
            bf16x8 a0 = *(const bf16x8*)(tA0 + kk * 32);
            bf16x8 a1 = *(const bf16x8*)(tA1 + kk * 32);
            size_t bo = ((size_t)(kk * 8 + g) * 64 + lane) * 8;
            bf16x8 bh = *(const bf16x8*)(B1h + bo);
            bf16x8 bl = *(const bf16x8*)(B1l + bo);
            acc0 = __builtin_amdgcn_mfma_f32_16x16x32_bf16(a0, bh, acc0, 0, 0, 0);
            acc0 = __builtin_amdgcn_mfma_f32_16x16x32_bf16(a0, bl, acc0, 0, 0, 0);
            acc1 = __builtin_amdgcn_mfma_f32_16x16x32_bf16(a1, bh, acc1, 0, 0, 0);
            acc1 = __builtin_amdgcn_mfma_f32_16x16x32_bf16(a1, bl, acc1, 0, 0, 0);
        }
    };

    // ---- fused layer1(TS part) || gather pipeline ----
    if (nfull > 0) issue8(i40);
    kk4(0);
    if (nfull > 0) acc8();
    if (nfull > 1) issue8(i41);
    kk4(4);
    if (nfull > 1) acc8();
    if (nfull > 2) issue8(i42);
    kk4(8);
    if (nfull > 2) acc8();
    if (nfull > 3) issue8(i43);
    kk4(12);
    if (nfull > 3) acc8();
    for (int b = 4; b < nfull; ++b) {           // residual full batches (c>32)
        uint4 i4 = *(const uint4*)(crow + b * 8);
        issue8(i4);
        acc8();
    }
    {
        int j = nfull * 8;
        if (j < c) {                            // predicated partial tail
            uint4 i4 = *(const uint4*)(crow + j);
            u32 w[4] = {i4.x, i4.y, i4.z, i4.w};
#pragma unroll
            for (int k = 0; k < 8; ++k) {
                int s = (int)((w[k >> 1] >> ((k & 1) * 16)) & 0xffffu);
                bool live = (j + k) < c;
                s = live ? s : 0;
                uint4 p = GHLoad(s);
                if (live) ACC(p);
            }
        }
    }
#undef ACC

    // ---- SAG store (agg hi/lo) ----
    {
        float inv = (ctrue > 0) ? 1.f / (float)ctrue : 0.f;
        int base = (gr * 136 + cg * 8) >> 1;   // u32 index (even)
        u32* SH = (u32*)SAGh;
        u32* SL = (u32*)SAGl;
#pragma unroll
        for (int p = 0; p < 4; ++p) {
            float x = a[2 * p] * inv, y = a[2 * p + 1] * inv;
            u16 hx = f2b(x), hy = f2b(y);
            SH[base + p] = (u32)hx | ((u32)hy << 16);
            SL[base + p] = (u32)f2b(x - b2f(hx)) | ((u32)f2b(y - b2f(hy)) << 16);
        }
    }
    __syncthreads();   // SAG ready; also: all TS reads complete before this

    // ---- layer1 agg part: kk16..19 from SAG ----
#pragma unroll
    for (int kk = 16; kk < 20; ++kk) {
        int o = (kk - 16) * 32;
        bf16x8 ah0 = *(const bf16x8*)(SAGh + hr0 + o);
        bf16x8 al0 = *(const bf16x8*)(SAGl + hr0 + o);
        bf16x8 ah1 = *(const bf16x8*)(SAGh + hr1 + o);
        bf16x8 al1 = *(const bf16x8*)(SAGl + hr1 + o);
        size_t bo = ((size_t)(kk * 8 + g) * 64 + lane) * 8;
        bf16x8 bh = *(const bf16x8*)(B1h + bo);
        bf16x8 bl = *(const bf16x8*)(B1l + bo);
        acc0 = __builtin_amdgcn_mfma_f32_16x16x32_bf16(ah0, bh, acc0, 0, 0, 0);
        acc0 = __builtin_amdgcn_mfma_f32_16x16x32_bf16(ah0, bl, acc0, 0, 0, 0);
        acc0 = __builtin_amdgcn_mfma_f32_16x16x32_bf16(al0, bh, acc0, 0, 0, 0);
        acc1 = __builtin_amdgcn_mfma_f32_16x16x32_bf16(ah1, bh, acc1, 0, 0, 0);
        acc1 = __builtin_amdgcn_mfma_f32_16x16x32_bf16(ah1, bl, acc1, 0, 0, 0);
        acc1 = __builtin_amdgcn_mfma_f32_16x16x32_bf16(al1, bh, acc1, 0, 0, 0);
    }
    // S1 write overlays TS: safe — every wave's TS reads precede the barrier
    {
        int n = g * 16 + n16;
        float bias = b1[n];
#pragma unroll
        for (int rg = 0; rg < 4; ++rg) {
            float v0 = acc0[rg] + bias; v0 = v0 > 0.f ? v0 : 0.f;
            float v1 = acc1[rg] + bias; v1 = v1 > 0.f ? v1 : 0.f;
            u16 h0 = f2b(v0), h1v = f2b(v1);
            S1h[(cr0 + rg) * 136 + n] = h0; S1l[(cr0 + rg) * 136 + n] = f2b(v0 - b2f(h0));
            S1h[(cr1 + rg) * 136 + n] = h1v; S1l[(cr1 + rg) * 136 + n] = f2b(v1 - b2f(h1v));
        }
    }
    __syncthreads();

    // ---- layer2: K=256 (h1 kk0..3 S1; agg kk4..7 SAG) ----
    acc0 = z4; acc1 = z4;
#pragma unroll
    for (int kk = 0; kk < 8; ++kk) {
        const u16* Ph = (kk < 4) ? S1h : SAGh;
        const u16* Pl = (kk < 4) ? S1l : SAGl;
        int o = (kk & 3) * 32;
        bf16x8 ah0 = *(const bf16x8*)(Ph + hr0 + o);
        bf16x8 al0 = *(const bf16x8*)(Pl + hr0 + o);
        bf16x8 ah1 = *(const bf16x8*)(Ph + hr1 + o);
        bf16x8 al1 = *(const bf16x8*)(Pl + hr1 + o);
        size_t bo = ((size_t)(kk * 8 + g) * 64 + lane) * 8;
        bf16x8 bh = *(const bf16x8*)(B2h + bo);
        bf16x8 bl = *(const bf16x8*)(B2l + bo);
        acc0 = __builtin_amdgcn_mfma_f32_16x16x32_bf16(ah0, bh, acc0, 0, 0, 0);
        acc0 = __builtin_amdgcn_mfma_f32_16x16x32_bf16(ah0, bl, acc0, 0, 0, 0);
        acc0 = __builtin_amdgcn_mfma_f32_16x16x32_bf16(al0, bh, acc0, 0, 0, 0);
        acc1 = __builtin_amdgcn_mfma_f32_16x16x32_bf16(ah1, bh, acc1, 0, 0, 0);
        acc1 = __builtin_amdgcn_mfma_f32_16x16x32_bf16(ah1, bl, acc1, 0, 0, 0);
        acc1 = __builtin_amdgcn_mfma_f32_16x16x32_bf16(al1, bh, acc1, 0, 0, 0);
    }
    {
        int n = g * 16 + n16;
        float bias = b2[n];
#pragma unroll
        for (int rg = 0; rg < 4; ++rg) {
            float v0 = acc0[rg] + bias; v0 = v0 > 0.f ? v0 : 0.f;
            float v1 = acc1[rg] + bias; v1 = v1 > 0.f ? v1 : 0.f;
            u16 h0 = f2b(v0), h1v = f2b(v1);
            S2h[(cr0 + rg) * 136 + n] = h0; S2l[(cr0 + rg) * 136 + n] = f2b(v0 - b2f(h0));
            S2h[(cr1 + rg) * 136 + n] = h1v; S2l[(cr1 + rg) * 136 + n] = f2b(v1 - b2f(h1v));
        }
    }
    __syncthreads();

    // ---- layer3: K=128 (h2 S2) -> S1 ----
    acc0 = z4; acc1 = z4;
#pragma unroll
    for (int kk = 0; kk < 4; ++kk) {
        int o = kk * 32;
        bf16x8 ah0 = *(const bf16x8*)(S2h + hr0 + o);
        bf16x8 al0 = *(const bf16x8*)(S2l + hr0 + o);
        bf16x8 ah1 = *(const bf16x8*)(S2h + hr1 + o);
        bf16x8 al1 = *(const bf16x8*)(S2l + hr1 + o);
        size_t bo = ((size_t)(kk * 8 + g) * 64 + lane) * 8;
        bf16x8 bh = *(const bf16x8*)(B3h + bo);
        bf16x8 bl = *(const bf16x8*)(B3l + bo);
        acc0 = __builtin_amdgcn_mfma_f32_16x16x32_bf16(ah0, bh, acc0, 0, 0, 0);
        acc0 = __builtin_amdgcn_mfma_f32_16x16x32_bf16(ah0, bl, acc0, 0, 0, 0);
        acc0 = __builtin_amdgcn_mfma_f32_16x16x32_bf16(al0, bh, acc0, 0, 0, 0);
        acc1 = __builtin_amdgcn_mfma_f32_16x16x32_bf16(ah1, bh, acc1, 0, 0, 0);
        acc1 = __builtin_amdgcn_mfma_f32_16x16x32_bf16(ah1, bl, acc1, 0, 0, 0);
        acc1 = __builtin_amdgcn_mfma_f32_16x16x32_bf16(al1, bh, acc1, 0, 0, 0);
    }
    {
        int n = g * 16 + n16;
        float bias = bc1[n];
#pragma unroll
        for (int rg = 0; rg < 4; ++rg) {
            float v0 = acc0[rg] + bias; v0 = v0 > 0.f ? v0 : 0.f;
            float v1 = acc1[rg] + bias; v1 = v1 > 0.f ? v1 : 0.f;
            u16 h0 = f2b(v0), h1v = f2b(v1);
            S1h[(cr0 + rg) * 136 + n] = h0; S1l[(cr0 + rg) * 136 + n] = f2b(v0 - b2f(h0));
            S1h[(cr1 + rg) * 136 + n] = h1v; S1l[(cr1 + rg) * 136 + n] = f2b(v1 - b2f(h1v));
        }
    }
    __syncthreads();

    // ---- layer4: K=128, N=16 (waves 0,1 = tiles 0,1) ----
    if (g < 2) {
        int hr = (g == 0) ? hr0 : hr1;
        int cr = (g == 0) ? cr0 : cr1;
        f32x4 a4 = z4;
#pragma unroll
        for (int kk = 0; kk < 4; ++kk) {
            bf16x8 ah = *(const bf16x8*)(S1h + hr + kk * 32);
            bf16x8 al = *(const bf16x8*)(S1l + hr + kk * 32);
            size_t bo = ((size_t)kk * 64 + lane) * 8;
            bf16x8 bh = *(const bf16x8*)(B4h + bo);
            bf16x8 bl = *(const bf16x8*)(B4l + bo);
            a4 = __builtin_amdgcn_mfma_f32_16x16x32_bf16(ah, bh, a4, 0, 0, 0);
            a4 = __builtin_amdgcn_mfma_f32_16x16x32_bf16(ah, bl, a4, 0, 0, 0);
            a4 = __builtin_amdgcn_mfma_f32_16x16x32_bf16(al, bh, a4, 0, 0, 0);
        }
        float bias = bc2[n16];
#pragma unroll
        for (int rg = 0; rg < 4; ++rg)
            out[(size_t)(row0 + cr + rg) * NCLS + n16] = a4[rg] + bias;
    }
}

extern "C" void kernel_launch(void* const* d_in, const int* in_sizes, int n_in,
                              void* d_out, int out_size, void* d_ws, size_t ws_size,
                              hipStream_t stream) {
    const float* gene = (const float*)d_in[0];
    const float* train = (const float*)d_in[1];
    const int* esrc = (const int*)d_in[2];
    const int* edst = (const int*)d_in[3];

    char* ws = (char*)d_ws;
    int* cnt = (int*)(ws + 0);              //    80000
    u16* csr = (u16*)(ws + 80000);          //  3840000
    u16* GH = (u16*)(ws + 3920000);         //   640000 (2500*128 u16)
    u16* B1h = (u16*)(ws + 4560000);        //   163840
    u16* B1l = (u16*)(ws + 4723840);        //   163840
    u16* B2h = (u16*)(ws + 4887680);        //    65536
    u16* B2l = (u16*)(ws + 4953216);        //    65536
    u16* B3h = (u16*)(ws + 5018752);        //    32768
    u16* B3l = (u16*)(ws + 5051520);        //    32768
    u16* B4h = (u16*)(ws + 5084288);        //     4096
    u16* B4l = (u16*)(ws + 5088384);        //     4096
    // total 5,092,480 B

    hipMemsetAsync(cnt, 0, NT * sizeof(int), stream);
    k_prep<<<NEB + GNB + PKB, 256, 0, stream>>>(
        esrc, edst, cnt, csr, gene, (u32*)GH,
        (const float*)d_in[4], (const float*)d_in[5], (const float*)d_in[7],
        (const float*)d_in[8], (const float*)d_in[10], (const float*)d_in[12],
        B1h, B1l, B2h, B2l, B3h, B3l, B4h, B4l);
    k_mega<<<NT / 32, 512, 0, stream>>>(
        cnt, csr, GH, train, B1h, B1l, B2h, B2l, B3h, B3l, B4h, B4l,
        (const float*)d_in[6], (const float*)d_in[9], (const float*)d_in[11],
        (const float*)d_in[13], (float*)d_out);
}